// Round 11
// baseline (167.499 us; speedup 1.0000x reference)
//
#include <hip/hip_runtime.h>
#include <hip/hip_bf16.h>

#define NEXP 8
#define NEMB 1024
#define NTOK 8192
#define BM 128
#define BN 128
#define BK 64
#define NK  (NEMB / BK)   // 16
#define BLD_STRIPE 512
#define MAXSLOTS 144

typedef __attribute__((ext_vector_type(8))) short  bf16x8;
typedef __attribute__((ext_vector_type(8))) unsigned short u16x8;
typedef __attribute__((ext_vector_type(4))) float  f32x4;

// ---- workspace layout (bytes) ----
#define XB_BYTES   (NTOK * NEMB * 2)
#define WB_BYTES   (NEXP * NEMB * NEMB * 2)
#define CNT_OFF    (XB_BYTES + WB_BYTES)
#define LTOK_OFF   (CNT_OFF + 256)
#define LWT_OFF    (LTOK_OFF + NEXP * NTOK * 4)
#define SELW_OFF   (LWT_OFF + NEXP * NTOK * 4)
#define META_OFF   (SELW_OFF + NTOK * 16)      // int meta[16 + MAXSLOTS]

__device__ __forceinline__ unsigned short f2bf(float f) {
    unsigned u = __builtin_bit_cast(unsigned, f);
    unsigned r = (u + 0x7fffu + ((u >> 16) & 1u)) >> 16;
    return (unsigned short)r;
}

// ---------------- expert_w fp32 -> bf16 ----------------
__global__ void k_cvt_w(const float* __restrict__ w, unsigned short* __restrict__ wb) {
    int i = (blockIdx.x * blockDim.x + threadIdx.x) * 8;
    f32x4 v0 = *reinterpret_cast<const f32x4*>(w + i);
    f32x4 v1 = *reinterpret_cast<const f32x4*>(w + i + 4);
    u16x8 o;
#pragma unroll
    for (int j = 0; j < 4; ++j) { o[j] = f2bf(v0[j]); o[4 + j] = f2bf(v1[j]); }
    *reinterpret_cast<u16x8*>(wb + i) = o;
}

// ---------------- gating: pure streaming, no atomics ----------------
__global__ __launch_bounds__(256)
void k_gate(const float* __restrict__ x, const float* __restrict__ gw,
            unsigned short* __restrict__ xb, int4* __restrict__ selw) {
    int t = threadIdx.x, wave = t >> 6, lane = t & 63;
    int n = blockIdx.x * 4 + wave;

    const float* xr = x + (size_t)n * NEMB + lane * 16;
    f32x4 xv[4];
#pragma unroll
    for (int j = 0; j < 4; ++j) xv[j] = *reinterpret_cast<const f32x4*>(xr + j * 4);

    u16x8 o0, o1;
#pragma unroll
    for (int q = 0; q < 4; ++q) {
        o0[q] = f2bf(xv[0][q]); o0[4 + q] = f2bf(xv[1][q]);
        o1[q] = f2bf(xv[2][q]); o1[4 + q] = f2bf(xv[3][q]);
    }
    u16x8* xo = reinterpret_cast<u16x8*>(xb + (size_t)n * NEMB + lane * 16);
    xo[0] = o0; xo[1] = o1;

    float p[NEXP];
#pragma unroll
    for (int e = 0; e < NEXP; ++e) {
        const float* gr = gw + e * NEMB + lane * 16;
        f32x4 a = xv[0] * *reinterpret_cast<const f32x4*>(gr);
#pragma unroll
        for (int j = 1; j < 4; ++j) a += xv[j] * *reinterpret_cast<const f32x4*>(gr + j * 4);
        p[e] = a[0] + a[1] + a[2] + a[3];
    }
#pragma unroll
    for (int e = 0; e < NEXP; ++e) {
        float v = p[e];
#pragma unroll
        for (int m = 1; m < 64; m <<= 1) v += __shfl_xor(v, m, 64);
        p[e] = v;
    }
    if (lane == 0) {
        int e0 = 0; float b0 = p[0];
#pragma unroll
        for (int e = 1; e < NEXP; ++e) if (p[e] > b0) { b0 = p[e]; e0 = e; }
        int e1 = -1; float b1 = -3.4e38f;
#pragma unroll
        for (int e = 0; e < NEXP; ++e) if (e != e0 && p[e] > b1) { b1 = p[e]; e1 = e; }
        float ex = __expf(b1 - b0);
        float inv = 1.f / (1.f + ex);
        int4 s;
        s.x = e0; s.y = e1;
        s.z = __float_as_int(inv); s.w = __float_as_int(ex * inv);
        selw[n] = s;
    }
}

// ---------------- build combined per-expert token list ----------------
__global__ __launch_bounds__(256)
void k_build(const int4* __restrict__ selw, int* __restrict__ counts,
             int* __restrict__ ltok, float* __restrict__ lwt) {
    int e = blockIdx.y;
    int n0 = blockIdx.x * BLD_STRIPE;
    __shared__ int lcnt, base;
    __shared__ int   toks[BLD_STRIPE];
    __shared__ float wts[BLD_STRIPE];
    if (threadIdx.x == 0) lcnt = 0;
    __syncthreads();
    for (int i = threadIdx.x; i < BLD_STRIPE; i += 256) {
        int4 s = selw[n0 + i];
        if (s.x == e) {
            int p = atomicAdd(&lcnt, 1);
            toks[p] = n0 + i; wts[p] = __int_as_float(s.z);
        }
        if (s.y == e) {
            int p = atomicAdd(&lcnt, 1);
            toks[p] = n0 + i; wts[p] = __int_as_float(s.w);
        }
    }
    __syncthreads();
    if (threadIdx.x == 0) base = atomicAdd(&counts[e], lcnt);
    __syncthreads();
    for (int i = threadIdx.x; i < lcnt; i += 256) {
        ltok[e * NTOK + base + i] = toks[i];
        lwt[e * NTOK + base + i]  = wts[i];
    }
}

// ---------------- pad lists + build tile worklist ----------------
// meta[0] = T, meta[1..8] = offs (unused for now), meta[16 + s] = (e<<16)|rb
__global__ void k_padW(const int* __restrict__ counts, int* __restrict__ ltok,
                       float* __restrict__ lwt, int* __restrict__ meta) {
    __shared__ int nt[NEXP], offs_s[NEXP];
    int t = threadIdx.x;
    if (t < NEXP) nt[t] = (counts[t] + BM - 1) / BM;
    __syncthreads();
    if (t == 0) {
        int T = 0;
        for (int e = 0; e < NEXP; ++e) { offs_s[e] = T; T += nt[e]; }
        meta[0] = T;
        for (int e = 0; e < NEXP; ++e) meta[1 + e] = offs_s[e];
    }
    __syncthreads();
    for (int e = 0; e < NEXP; ++e) {
        for (int j = t; j < nt[e]; j += 256)
            meta[16 + offs_s[e] + j] = (e << 16) | j;
        int c = counts[e], cp = nt[e] * BM;
        for (int i = c + t; i < cp; i += 256) {
            ltok[e * NTOK + i] = -1;
            lwt[e * NTOK + i]  = 0.f;
        }
    }
}

// ---------------- grouped gathered GEMM: 4-phase counted-vmcnt, 2 blocks/CU -------------
// 128x128 tile, BK=64, 4 waves (2Mx2N, per-wave 64x64 = acc[4][4]).
// LDS piece layout (phys rows): A piece mh = rows [mh*64, mh*64+63]; phys row
//   d = mh*64 + wr*32 + m*16 + fr  <->  logical tile row = wr*64 + mh*32 + m*16 + fr.
// Phase p reads exactly one new piece; stage order per K-tile k (all -> k+1):
//   P1: sA0; vm(4); bar; read af(mh0)+bf0(nh0); MM(0,0)
//   P2: sA1; vm(4); bar; read bf1(nh1);          MM(0,1)
//   P3: sB0; vm(6); bar; read af(mh1);           MM(1,0)
//   P4: sB1;                       (reg reuse)   MM(1,1)
// vmcnt ladder verified: entering P1 outstanding = {A0,A1,B0,B1}(k) = 8 instr;
// P1 drains to {B1(k),A0(k+1)}; P2 drains B1(k); P3 no-op. Never drains to 0.
// Swizzle: LDS (d, c) holds global chunk c^(d&7); read chunk (ks*4+fq)^(fr&7).
__global__ __launch_bounds__(256)
void k_gemm(const unsigned short* __restrict__ xb, const unsigned short* __restrict__ wb,
            const int* __restrict__ ltok, const float* __restrict__ lwt,
            const int* __restrict__ meta, float* __restrict__ out) {
    int T = meta[0];
    int slot = blockIdx.y;
    if (slot >= T) return;
    int wle = meta[16 + slot];
    int e = wle >> 16, rb = wle & 0xffff;
    int cb = blockIdx.x;

    __shared__ unsigned short As[2][BM * BK];   // 2 x 16 KB
    __shared__ unsigned short Bs[2][BN * BK];   // 2 x 16 KB
    __shared__ int   tokS[BM];
    __shared__ float wS[BM];

    int t = threadIdx.x, lane = t & 63, wave = t >> 6;
    int wr = wave >> 1, wc = wave & 1;
    int fr = lane & 15, fq = lane >> 4, f7 = fr & 7;

    if (t < BM) {
        tokS[t] = ltok[e * NTOK + rb * BM + t];
        wS[t]   = lwt[e * NTOK + rb * BM + t];
    }

    // staging sources: piece p, chunk group i -> phys row d, permuted logical row
    const unsigned short* aSrc[2][2];
    const unsigned short* bSrc[2][2];
#pragma unroll
    for (int p = 0; p < 2; ++p)
#pragma unroll
        for (int i = 0; i < 2; ++i) {
            int d    = p * 64 + i * 32 + (t >> 3);
            int csw  = (t & 7) ^ (d & 7);
            int lrow = ((d >> 5) & 1) * 64 + (d >> 6) * 32 + (d & 31);
            int tok  = ltok[e * NTOK + rb * BM + lrow];
            int tokc = tok < 0 ? 0 : tok;
            aSrc[p][i] = xb + (size_t)tokc * NEMB + csw * 8;
            bSrc[p][i] = wb + (size_t)e * NEMB * NEMB
                            + (size_t)(cb * BN + lrow) * NEMB + csw * 8;
        }
    __syncthreads();    // tokS visible; ALL prior VMEM drained (vmcnt=0 baseline)

#define GLL(src, dst)                                                                \
    __builtin_amdgcn_global_load_lds(                                                \
        (const __attribute__((address_space(1))) void*)(src),                        \
        (__attribute__((address_space(3))) void*)(dst), 16, 0, 0)
#define SA(buf, p, kt) {                                                             \
    GLL(aSrc[p][0] + (kt) * BK, &As[buf][(p) * 4096 + wave * 512]);                  \
    GLL(aSrc[p][1] + (kt) * BK, &As[buf][(p) * 4096 + 2048 + wave * 512]); }
#define SB(buf, p, kt) {                                                             \
    GLL(bSrc[p][0] + (kt) * BK, &Bs[buf][(p) * 4096 + wave * 512]);                  \
    GLL(bSrc[p][1] + (kt) * BK, &Bs[buf][(p) * 4096 + 2048 + wave * 512]); }
#define RDA(MH, buf) { _Pragma("unroll") for (int m = 0; m < 2; ++m)                 \
    { _Pragma("unroll") for (int ks = 0; ks < 2; ++ks)                               \
        af[m][ks] = *reinterpret_cast<const bf16x8*>(                                \
            &As[buf][((MH) * 64 + wr * 32 + m * 16 + fr) * BK                        \
                     + (((ks * 4 + fq) ^ f7) * 8)]); } }
#define RDB(DST, NH, buf) { _Pragma("unroll") for (int n = 0; n < 2; ++n)            \
    { _Pragma("unroll") for (int ks = 0; ks < 2; ++ks)                               \
        DST[n][ks] = *reinterpret_cast<const bf16x8*>(                               \
            &Bs[buf][((NH) * 64 + wc * 32 + n * 16 + fr) * BK                        \
                     + (((ks * 4 + fq) ^ f7) * 8)]); } }
#define MM(MH, NH, BF) { __builtin_amdgcn_s_setprio(1);                              \
    _Pragma("unroll") for (int m = 0; m < 2; ++m)                                    \
    { _Pragma("unroll") for (int n = 0; n < 2; ++n) {                                \
        acc[(MH)*2+m][(NH)*2+n] = __builtin_amdgcn_mfma_f32_16x16x32_bf16(           \
            af[m][0], BF[n][0], acc[(MH)*2+m][(NH)*2+n], 0, 0, 0);                   \
        acc[(MH)*2+m][(NH)*2+n] = __builtin_amdgcn_mfma_f32_16x16x32_bf16(           \
            af[m][1], BF[n][1], acc[(MH)*2+m][(NH)*2+n], 0, 0, 0); } }               \
    __builtin_amdgcn_s_setprio(0); }
#define BAR   __builtin_amdgcn_s_barrier()
#define LGKM0 { asm volatile("s_waitcnt lgkmcnt(0)" ::: "memory");                   \
                __builtin_amdgcn_sched_barrier(0); }

    f32x4 acc[4][4];
#pragma unroll
    for (int m = 0; m < 4; ++m)
#pragma unroll
        for (int n = 0; n < 4; ++n) acc[m][n] = (f32x4){0.f, 0.f, 0.f, 0.f};

    bf16x8 af[2][2], bf0[2][2], bf1[2][2];

    // prologue: tile 0, pieces in canonical order (8 instr outstanding)
    SA(0, 0, 0); SA(0, 1, 0); SB(0, 0, 0); SB(0, 1, 0);

    for (int kt = 0; kt < NK - 1; ++kt) {
        int buf = kt & 1, nb = buf ^ 1;
        // P1
        SA(nb, 0, kt + 1);
        asm volatile("s_waitcnt vmcnt(4)" ::: "memory");
        BAR;
        RDA(0, buf); RDB(bf0, 0, buf);
        LGKM0; MM(0, 0, bf0);
        // P2
        SA(nb, 1, kt + 1);
        asm volatile("s_waitcnt vmcnt(4)" ::: "memory");
        BAR;
        RDB(bf1, 1, buf);
        LGKM0; MM(0, 1, bf1);
        // P3
        SB(nb, 0, kt + 1);
        asm volatile("s_waitcnt vmcnt(6)" ::: "memory");
        BAR;
        RDA(1, buf);
        LGKM0; MM(1, 0, bf0);
        // P4 (register reuse only)
        SB(nb, 1, kt + 1);
        MM(1, 1, bf1);
    }
    // tail: kt = NK-1, buf = (NK-1)&1 = 1; no new stages
    asm volatile("s_waitcnt vmcnt(2)" ::: "memory");
    BAR;
    RDA(0, 1); RDB(bf0, 0, 1);
    LGKM0; MM(0, 0, bf0);
    asm volatile("s_waitcnt vmcnt(0)" ::: "memory");
    BAR;
    RDB(bf1, 1, 1);
    LGKM0; MM(0, 1, bf1);
    RDA(1, 1);
    LGKM0; MM(1, 0, bf0);
    MM(1, 1, bf1);

#undef GLL
#undef SA
#undef SB
#undef RDA
#undef RDB
#undef MM
#undef BAR
#undef LGKM0

    // epilogue: weighted atomic scatter (each out element receives exactly 2 adds)
#pragma unroll
    for (int M = 0; M < 4; ++M) {
#pragma unroll
        for (int jj = 0; jj < 4; ++jj) {
            int row = wr * 64 + M * 16 + fq * 4 + jj;
            int tok = tokS[row];
            if (tok < 0) continue;
            float wgt = wS[row];
            float* orow = out + (size_t)tok * NEMB + cb * BN + wc * 64 + fr;
#pragma unroll
            for (int n = 0; n < 4; ++n)
                unsafeAtomicAdd(orow + n * 16, wgt * acc[M][n][jj]);
        }
    }
}

extern "C" void kernel_launch(void* const* d_in, const int* in_sizes, int n_in,
                              void* d_out, int out_size, void* d_ws, size_t ws_size,
                              hipStream_t stream) {
    const float* x  = (const float*)d_in[0];
    const float* gw = (const float*)d_in[1];
    const float* ew = (const float*)d_in[2];
    float* out = (float*)d_out;

    char* ws = (char*)d_ws;
    unsigned short* xb = (unsigned short*)(ws);
    unsigned short* wb = (unsigned short*)(ws + XB_BYTES);
    int*   counts = (int*)(ws + CNT_OFF);
    int*   ltok   = (int*)(ws + LTOK_OFF);
    float* lwt    = (float*)(ws + LWT_OFF);
    int4*  selw   = (int4*)(ws + SELW_OFF);
    int*   meta   = (int*)(ws + META_OFF);

    hipMemsetAsync(counts, 0, 8 * sizeof(int), stream);
    hipMemsetAsync(out, 0, (size_t)NTOK * NEMB * sizeof(float), stream);

    k_cvt_w<<<4096, 256, 0, stream>>>(ew, wb);
    k_gate<<<NTOK / 4, 256, 0, stream>>>(x, gw, xb, selw);
    k_build<<<dim3(NTOK / BLD_STRIPE, NEXP), 256, 0, stream>>>(selw, counts, ltok, lwt);
    k_padW<<<1, 256, 0, stream>>>(counts, ltok, lwt, meta);
    // worklist grid: 8 cb x 144 slots (T <= 135); inactive slots exit on meta[0]
    k_gemm<<<dim3(NEMB / BN, MAXSLOTS), 256, 0, stream>>>(xb, wb, ltok, lwt, meta, out);
}

// Round 12
// 137.721 us; speedup vs baseline: 1.2162x; 1.2162x over previous
//
#include <hip/hip_runtime.h>
#include <hip/hip_bf16.h>

#define NEXP 8
#define NEMB 1024
#define NTOK 8192
#define BM 128
#define BN 128
#define BK 64
#define NK  (NEMB / BK)   // 16
#define RBS 24            // max row-tiles per expert slot
#define BLD_STRIPE 512

typedef __attribute__((ext_vector_type(8))) short  bf16x8;
typedef __attribute__((ext_vector_type(8))) unsigned short u16x8;
typedef __attribute__((ext_vector_type(4))) float  f32x4;

// ---- workspace layout (bytes) ----
#define XB_BYTES   (NTOK * NEMB * 2)
#define WB_BYTES   (NEXP * NEMB * NEMB * 2)
#define CNT_OFF    (XB_BYTES + WB_BYTES)
#define LTOK_OFF   (CNT_OFF + 256)
#define LWT_OFF    (LTOK_OFF + NEXP * NTOK * 4)
#define SELW_OFF   (LWT_OFF + NEXP * NTOK * 4)
#define META_OFF   (SELW_OFF + NTOK * 16)      // int meta[16]: meta[1+e] = nt[e]

__device__ __forceinline__ unsigned short f2bf(float f) {
    unsigned u = __builtin_bit_cast(unsigned, f);
    unsigned r = (u + 0x7fffu + ((u >> 16) & 1u)) >> 16;
    return (unsigned short)r;
}

// ---------------- expert_w fp32 -> bf16 ----------------
__global__ void k_cvt_w(const float* __restrict__ w, unsigned short* __restrict__ wb) {
    int i = (blockIdx.x * blockDim.x + threadIdx.x) * 8;
    f32x4 v0 = *reinterpret_cast<const f32x4*>(w + i);
    f32x4 v1 = *reinterpret_cast<const f32x4*>(w + i + 4);
    u16x8 o;
#pragma unroll
    for (int j = 0; j < 4; ++j) { o[j] = f2bf(v0[j]); o[4 + j] = f2bf(v1[j]); }
    *reinterpret_cast<u16x8*>(wb + i) = o;
}

// ---------------- gating: pure streaming, no atomics ----------------
__global__ __launch_bounds__(256)
void k_gate(const float* __restrict__ x, const float* __restrict__ gw,
            unsigned short* __restrict__ xb, int4* __restrict__ selw) {
    int t = threadIdx.x, wave = t >> 6, lane = t & 63;
    int n = blockIdx.x * 4 + wave;

    const float* xr = x + (size_t)n * NEMB + lane * 16;
    f32x4 xv[4];
#pragma unroll
    for (int j = 0; j < 4; ++j) xv[j] = *reinterpret_cast<const f32x4*>(xr + j * 4);

    u16x8 o0, o1;
#pragma unroll
    for (int q = 0; q < 4; ++q) {
        o0[q] = f2bf(xv[0][q]); o0[4 + q] = f2bf(xv[1][q]);
        o1[q] = f2bf(xv[2][q]); o1[4 + q] = f2bf(xv[3][q]);
    }
    u16x8* xo = reinterpret_cast<u16x8*>(xb + (size_t)n * NEMB + lane * 16);
    xo[0] = o0; xo[1] = o1;

    float p[NEXP];
#pragma unroll
    for (int e = 0; e < NEXP; ++e) {
        const float* gr = gw + e * NEMB + lane * 16;
        f32x4 a = xv[0] * *reinterpret_cast<const f32x4*>(gr);
#pragma unroll
        for (int j = 1; j < 4; ++j) a += xv[j] * *reinterpret_cast<const f32x4*>(gr + j * 4);
        p[e] = a[0] + a[1] + a[2] + a[3];
    }
#pragma unroll
    for (int e = 0; e < NEXP; ++e) {
        float v = p[e];
#pragma unroll
        for (int m = 1; m < 64; m <<= 1) v += __shfl_xor(v, m, 64);
        p[e] = v;
    }
    if (lane == 0) {
        int e0 = 0; float b0 = p[0];
#pragma unroll
        for (int e = 1; e < NEXP; ++e) if (p[e] > b0) { b0 = p[e]; e0 = e; }
        int e1 = -1; float b1 = -3.4e38f;
#pragma unroll
        for (int e = 0; e < NEXP; ++e) if (e != e0 && p[e] > b1) { b1 = p[e]; e1 = e; }
        float ex = __expf(b1 - b0);
        float inv = 1.f / (1.f + ex);
        int4 s;
        s.x = e0; s.y = e1;
        s.z = __float_as_int(inv); s.w = __float_as_int(ex * inv);
        selw[n] = s;
    }
}

// ---------------- build combined per-expert token list ----------------
__global__ __launch_bounds__(256)
void k_build(const int4* __restrict__ selw, int* __restrict__ counts,
             int* __restrict__ ltok, float* __restrict__ lwt) {
    int e = blockIdx.y;
    int n0 = blockIdx.x * BLD_STRIPE;
    __shared__ int lcnt, base;
    __shared__ int   toks[BLD_STRIPE];
    __shared__ float wts[BLD_STRIPE];
    if (threadIdx.x == 0) lcnt = 0;
    __syncthreads();
    for (int i = threadIdx.x; i < BLD_STRIPE; i += 256) {
        int4 s = selw[n0 + i];
        if (s.x == e) {
            int p = atomicAdd(&lcnt, 1);
            toks[p] = n0 + i; wts[p] = __int_as_float(s.z);
        }
        if (s.y == e) {
            int p = atomicAdd(&lcnt, 1);
            toks[p] = n0 + i; wts[p] = __int_as_float(s.w);
        }
    }
    __syncthreads();
    if (threadIdx.x == 0) base = atomicAdd(&counts[e], lcnt);
    __syncthreads();
    for (int i = threadIdx.x; i < lcnt; i += 256) {
        ltok[e * NTOK + base + i] = toks[i];
        lwt[e * NTOK + base + i]  = wts[i];
    }
}

// ---------------- pad lists + publish per-expert tile counts ----------------
__global__ void k_padW(const int* __restrict__ counts, int* __restrict__ ltok,
                       float* __restrict__ lwt, int* __restrict__ meta) {
    __shared__ int nt[NEXP];
    int t = threadIdx.x;
    if (t < NEXP) {
        nt[t] = (counts[t] + BM - 1) / BM;
        meta[1 + t] = nt[t];
    }
    __syncthreads();
    for (int e = 0; e < NEXP; ++e) {
        int c = counts[e], cp = nt[e] * BM;
        for (int i = c + t; i < cp; i += 256) {
            ltok[e * NTOK + i] = -1;
            lwt[e * NTOK + i]  = 0.f;
        }
    }
}

// ---------------- grouped gathered GEMM: m97 geometry + XCD pin ----------------
// 128x128 tile, BK=64, SINGLE-buffer LDS (33 KB) -> 4 blocks/CU = 16 waves/CU.
// Plain drain loop (stage -> sync -> compute -> sync); cross-block TLP hides
// the stage latency (m97/m114 regime). Expert pinned to XCD via e = bid&7
// (R5-proven: B panel + A slice become L2-resident -> lower load latency ->
// higher per-wave staging rate). Swizzle: LDS chunk (r,c) holds global chunk
// c^(r&7); read chunk (fq+4ks)^(fr&7)  [0 conflicts, proven R4/R6].
__global__ __launch_bounds__(256)
void k_gemm(const unsigned short* __restrict__ xb, const unsigned short* __restrict__ wb,
            const int* __restrict__ ltok, const float* __restrict__ lwt,
            const int* __restrict__ meta, float* __restrict__ out) {
    int b  = blockIdx.x;
    int e  = b & 7;               // XCD pin: consecutive ids round-robin XCDs
    int j  = b >> 3;
    int cb = j & 7;
    int rb = j >> 3;              // 0..RBS-1
    if (rb >= meta[1 + e]) return;

    __shared__ unsigned short As[BM * BK];   // 16 KB
    __shared__ unsigned short Bs[BN * BK];   // 16 KB
    __shared__ int   tokS[BM];
    __shared__ float wS[BM];

    int t = threadIdx.x, lane = t & 63, wave = t >> 6;
    int wr = wave >> 1, wc = wave & 1;
    int fr = lane & 15, fq = lane >> 4, fs = fr & 7;

    if (t < BM) {
        tokS[t] = ltok[e * NTOK + rb * BM + t];
        wS[t]   = lwt[e * NTOK + rb * BM + t];
    }

    const unsigned short* aSrc[4];
    const unsigned short* bSrc[4];
    int ldsOff[4];
#pragma unroll
    for (int i = 0; i < 4; ++i) {
        int idx = i * 256 + t;
        int r   = idx >> 3;
        int csw = (idx & 7) ^ (r & 7);
        int tok = ltok[e * NTOK + rb * BM + r];
        int tokc = tok < 0 ? 0 : tok;
        aSrc[i] = xb + (size_t)tokc * NEMB + csw * 8;
        bSrc[i] = wb + (size_t)e * NEMB * NEMB + (size_t)(cb * BN + r) * NEMB + csw * 8;
        ldsOff[i] = (i * 256 + wave * 64) * 8;   // wave-uniform base; HW adds lane*16B
    }

    f32x4 acc[4][4];
#pragma unroll
    for (int m = 0; m < 4; ++m)
#pragma unroll
        for (int n = 0; n < 4; ++n) acc[m][n] = (f32x4){0.f, 0.f, 0.f, 0.f};

    for (int kk = 0; kk < NK; ++kk) {
#pragma unroll
        for (int i = 0; i < 4; ++i) {
            __builtin_amdgcn_global_load_lds(
                (const __attribute__((address_space(1))) void*)(aSrc[i] + kk * BK),
                (__attribute__((address_space(3))) void*)(As + ldsOff[i]), 16, 0, 0);
            __builtin_amdgcn_global_load_lds(
                (const __attribute__((address_space(1))) void*)(bSrc[i] + kk * BK),
                (__attribute__((address_space(3))) void*)(Bs + ldsOff[i]), 16, 0, 0);
        }
        __syncthreads();    // drains vmcnt; staged tile visible to all waves

#pragma unroll
        for (int ks = 0; ks < 2; ++ks) {
            int ch = (fq + 4 * ks) ^ fs;
            bf16x8 af[4], bfr[4];
#pragma unroll
            for (int m = 0; m < 4; ++m)
                af[m] = *reinterpret_cast<const bf16x8*>(
                    As + (wr * 64 + m * 16 + fr) * BK + ch * 8);
#pragma unroll
            for (int n = 0; n < 4; ++n)
                bfr[n] = *reinterpret_cast<const bf16x8*>(
                    Bs + (wc * 64 + n * 16 + fr) * BK + ch * 8);
            __builtin_amdgcn_s_setprio(1);
#pragma unroll
            for (int m = 0; m < 4; ++m)
#pragma unroll
                for (int n = 0; n < 4; ++n)
                    acc[m][n] = __builtin_amdgcn_mfma_f32_16x16x32_bf16(
                        af[m], bfr[n], acc[m][n], 0, 0, 0);
            __builtin_amdgcn_s_setprio(0);
        }
        __syncthreads();    // all waves done reading before next stage overwrites
    }

    // epilogue: weighted atomic scatter (each out element receives exactly 2 adds)
#pragma unroll
    for (int m = 0; m < 4; ++m) {
#pragma unroll
        for (int jj = 0; jj < 4; ++jj) {
            int row = wr * 64 + m * 16 + fq * 4 + jj;
            int tok = tokS[row];
            if (tok < 0) continue;
            float wgt = wS[row];
            float* orow = out + (size_t)tok * NEMB + cb * BN + wc * 64 + fr;
#pragma unroll
            for (int n = 0; n < 4; ++n)
                unsafeAtomicAdd(orow + n * 16, wgt * acc[m][n][jj]);
        }
    }
}

extern "C" void kernel_launch(void* const* d_in, const int* in_sizes, int n_in,
                              void* d_out, int out_size, void* d_ws, size_t ws_size,
                              hipStream_t stream) {
    const float* x  = (const float*)d_in[0];
    const float* gw = (const float*)d_in[1];
    const float* ew = (const float*)d_in[2];
    float* out = (float*)d_out;

    char* ws = (char*)d_ws;
    unsigned short* xb = (unsigned short*)(ws);
    unsigned short* wb = (unsigned short*)(ws + XB_BYTES);
    int*   counts = (int*)(ws + CNT_OFF);
    int*   ltok   = (int*)(ws + LTOK_OFF);
    float* lwt    = (float*)(ws + LWT_OFF);
    int4*  selw   = (int4*)(ws + SELW_OFF);
    int*   meta   = (int*)(ws + META_OFF);

    hipMemsetAsync(counts, 0, 8 * sizeof(int), stream);
    hipMemsetAsync(out, 0, (size_t)NTOK * NEMB * sizeof(float), stream);

    k_cvt_w<<<4096, 256, 0, stream>>>(ew, wb);
    k_gate<<<NTOK / 4, 256, 0, stream>>>(x, gw, xb, selw);
    k_build<<<dim3(NTOK / BLD_STRIPE, NEXP), 256, 0, stream>>>(selw, counts, ltok, lwt);
    k_padW<<<1, 256, 0, stream>>>(counts, ltok, lwt, meta);
    // flat grid, expert = bid&7 (XCD pin): 8 e x 8 cb x RBS rb = 1536 slots
    k_gemm<<<8 * 8 * RBS, 256, 0, stream>>>(xb, wb, ltok, lwt, meta, out);
}